// Round 5
// baseline (244.502 us; speedup 1.0000x reference)
//
#include <hip/hip_runtime.h>

// Shapes (fixed): B=32, N=64, A=32, O=32, D=512, QD=512
// Inputs: 0:q(B,N,1,QD) f32  1:att1(B,N,A,O) f32  2:obj_reps(B,O,D) f32
//         3:tags(B,N,A) i32  4:t_rep(B,N,A,D) f32 5:W(QD,D) f32
//         6:bias f32 scalar  7:t i32 scalar
// Out: (B,N,O) f32
//
// Restructure: logits[bn,a] = sum_o att1[bn,a,o]*proj[bn,o] + inter[bn,:].t_rep[bn,a,:]
//   proj[bn,o] = inter[bn,:].obj_reps[b,o,:];  inter = q @ W
// Avoids materializing v (134 MB write+read). HBM floor ~= t_rep stream = 134 MB -> ~21 us.
// fp32 everywhere: logits std ~77 with near-one-hot softmax; bf16 noise can flip ties.
//
// Measurement model (R0-R4): dur_us ~= 195 us fixed harness traffic (512 MiB ws
// re-poison ~78 us + input restores) + ~40 us ours. R4's merged+nontemporal K2
// regressed +6.4 us vs R2's separate-loop K2 (register pressure halves outstanding
// HBM loads; nt bypass path slower). K2 reverted to R2 form; K1 keeps BK=64.

#define GM 2048   // B*N
#define GK 512    // QD
#define GN 512    // D

// ---------------- K1: inter = q @ W  (fp32 GEMM, 64x64 tile, BK=64, 4x4 microtile) ----
// 256 blocks = 1 block/CU (4 waves): barriers serialize fully, so BK=64 halves barrier
// count vs BK=32. A staged via register-transpose -> all LDS writes are ds_write_b128.
#define BM 64
#define BN 64
#define BK 64
#define ASTRIDE (BM + 4)   // 68: (k*68+m) with m%4==0 stays 16B-aligned for ds_read_b128

__global__ __launch_bounds__(256) void gemm_qw(const float* __restrict__ A,
                                               const float* __restrict__ Bm,
                                               float* __restrict__ C) {
    __shared__ float As[BK][ASTRIDE];   // [k][m]  17.4 KB
    __shared__ float Bs[BK][BN];        // [k][n]  16.4 KB

    const int tid = threadIdx.x;
    const int bm0 = blockIdx.y * BM;
    const int bn0 = blockIdx.x * BN;

    // A staging: 16 m-groups x 16 k-groups; each thread loads 4 rows x 4 k (reg transpose)
    const int tm = (tid & 15) << 2;     // m0 (0..60)
    const int tk = (tid >> 4) << 2;     // k0 within tile (0..60)
    // B staging: k rows br+16r, cols bc..bc+3
    const int br = tid >> 4;            // 0..15
    const int bc = (tid & 15) << 2;     // 0..60

    const int tx = tid & 15;            // output cols tx*4..+3
    const int ty = tid >> 4;            // output rows ty*4..+3

    float acc[4][4] = {};

    const float* Ab = A + (long)bm0 * GK;
    const float* Bb = Bm + bn0;

    float4 ag[4], bg[4];
#pragma unroll
    for (int r = 0; r < 4; ++r) {
        ag[r] = *(const float4*)(Ab + (tm + r) * GK + tk);
        bg[r] = *(const float4*)(Bb + (br + 16 * r) * GN + bc);
    }

    for (int k0 = 0; k0 < GK; k0 += BK) {
        __syncthreads();   // previous iteration's LDS reads done
        {   // A: transpose 4x4 in registers, write 4x ds_write_b128 to As[k][m]
            const float* a0 = (const float*)&ag[0];
            const float* a1 = (const float*)&ag[1];
            const float* a2 = (const float*)&ag[2];
            const float* a3 = (const float*)&ag[3];
#pragma unroll
            for (int jj = 0; jj < 4; ++jj)
                *(float4*)&As[tk + jj][tm] = make_float4(a0[jj], a1[jj], a2[jj], a3[jj]);
#pragma unroll
            for (int r = 0; r < 4; ++r)
                *(float4*)&Bs[br + 16 * r][bc] = bg[r];
        }
        __syncthreads();

        if (k0 + BK < GK) {   // register prefetch of next K-tile hides global latency
            const int kn = k0 + BK;
#pragma unroll
            for (int r = 0; r < 4; ++r) {
                ag[r] = *(const float4*)(Ab + (tm + r) * GK + kn + tk);
                bg[r] = *(const float4*)(Bb + (kn + br + 16 * r) * GN + bc);
            }
        }

#pragma unroll
        for (int kk = 0; kk < BK; ++kk) {
            float4 av = *(const float4*)&As[kk][ty * 4];   // broadcast across 16 lanes
            float4 bv = *(const float4*)&Bs[kk][tx * 4];   // 4-lane same-address replication
            acc[0][0] += av.x * bv.x; acc[0][1] += av.x * bv.y;
            acc[0][2] += av.x * bv.z; acc[0][3] += av.x * bv.w;
            acc[1][0] += av.y * bv.x; acc[1][1] += av.y * bv.y;
            acc[1][2] += av.y * bv.z; acc[1][3] += av.y * bv.w;
            acc[2][0] += av.z * bv.x; acc[2][1] += av.z * bv.y;
            acc[2][2] += av.z * bv.z; acc[2][3] += av.z * bv.w;
            acc[3][0] += av.w * bv.x; acc[3][1] += av.w * bv.y;
            acc[3][2] += av.w * bv.z; acc[3][3] += av.w * bv.w;
        }
    }

#pragma unroll
    for (int i = 0; i < 4; ++i) {
        float4 v = make_float4(acc[i][0], acc[i][1], acc[i][2], acc[i][3]);
        *(float4*)(C + (long)(bm0 + ty * 4 + i) * GN + bn0 + tx * 4) = v;
    }
}

// ---------------- K2: fused proj/tdot/logits/softmax/output (R2 form) ----------------
// Separate loops: obj_reps pass (L2-resident) then t_rep pass (HBM stream). Keeps
// register pressure low so all 16 t_rep float4 loads can be in flight. No nontemporal
// (R4 showed +6.4 us with merged+nt).
__global__ __launch_bounds__(256) void fused_att(
    const float* __restrict__ att1, const float* __restrict__ obj_reps,
    const int* __restrict__ tags, const float* __restrict__ t_rep,
    const float* __restrict__ inter, const float* __restrict__ bias_p,
    const int* __restrict__ t_p, float* __restrict__ out) {
    const int bn = blockIdx.x;     // 0..2047
    const int b  = bn >> 6;        // N = 64
    const int tid = threadIdx.x;

    __shared__ float inter_s[512];
    __shared__ float att1_s[32 * 33];   // +1 pad: bank-conflict-free rows & cols
    __shared__ float proj_s[32];
    __shared__ float tdot_s[32];
    __shared__ float att2_s[32];

    // stage inter row (512 f32) and att1 tile (32x32 f32, padded)
    {
        float2 v = *(const float2*)(inter + bn * 512 + tid * 2);
        inter_s[tid * 2 + 0] = v.x;
        inter_s[tid * 2 + 1] = v.y;
    }
    {
        float4 v = *(const float4*)(att1 + bn * 1024 + tid * 4);
        int f = tid * 4;
        int r = f >> 5, c = f & 31;
        att1_s[r * 33 + c + 0] = v.x;
        att1_s[r * 33 + c + 1] = v.y;
        att1_s[r * 33 + c + 2] = v.z;
        att1_s[r * 33 + c + 3] = v.w;
    }
    __syncthreads();

    const int g = tid >> 3;   // 0..31: one row per 8-thread group
    const int j = tid & 7;    // lane within group

    // proj[g] = inter . obj_reps[b,g,:]   (L2-resident: obj_reps is 2 MB)
    {
        const float* p = obj_reps + (b * 32 + g) * 512;
        float s = 0.f;
#pragma unroll
        for (int i = 0; i < 16; ++i) {
            int d = i * 32 + j * 4;
            float4 v = *(const float4*)(p + d);
            s += v.x * inter_s[d + 0] + v.y * inter_s[d + 1]
               + v.z * inter_s[d + 2] + v.w * inter_s[d + 3];
        }
        s += __shfl_xor(s, 1); s += __shfl_xor(s, 2); s += __shfl_xor(s, 4);
        if (j == 0) proj_s[g] = s;
    }
    // tdot[g] = inter . t_rep[bn,g,:]   (the HBM-dominant stream: 134 MB total)
    {
        const float* p = t_rep + (bn * 32 + g) * 512;
        float s = 0.f;
#pragma unroll
        for (int i = 0; i < 16; ++i) {
            int d = i * 32 + j * 4;
            float4 v = *(const float4*)(p + d);
            s += v.x * inter_s[d + 0] + v.y * inter_s[d + 1]
               + v.z * inter_s[d + 2] + v.w * inter_s[d + 3];
        }
        s += __shfl_xor(s, 1); s += __shfl_xor(s, 2); s += __shfl_xor(s, 4);
        if (j == 0) tdot_s[g] = s;
    }
    __syncthreads();

    // logits + masked softmax + renorm: threads 0..31 (all in wave 0)
    if (tid < 32) {
        const int a = tid;
        const float bias = *bias_p;
        const float tt = (float)(*t_p);
        float lsum = tdot_s[a] + bias;
#pragma unroll
        for (int o = 0; o < 32; ++o)
            lsum += att1_s[a * 33 + o] * proj_s[o];
        const float m = (float)tags[bn * 32 + a];
        float x = (lsum / tt) * m;     // masked slots -> logit 0, still in softmax
        float mx = x;
        mx = fmaxf(mx, __shfl_xor(mx, 1));
        mx = fmaxf(mx, __shfl_xor(mx, 2));
        mx = fmaxf(mx, __shfl_xor(mx, 4));
        mx = fmaxf(mx, __shfl_xor(mx, 8));
        mx = fmaxf(mx, __shfl_xor(mx, 16));
        float e = __expf(x - mx);
        float den = e;
        den += __shfl_xor(den, 1);
        den += __shfl_xor(den, 2);
        den += __shfl_xor(den, 4);
        den += __shfl_xor(den, 8);
        den += __shfl_xor(den, 16);
        float s = (e / den) * m;
        float ss = s;
        ss += __shfl_xor(ss, 1);
        ss += __shfl_xor(ss, 2);
        ss += __shfl_xor(ss, 4);
        ss += __shfl_xor(ss, 8);
        ss += __shfl_xor(ss, 16);
        att2_s[a] = s / (ss + 1e-13f);
    }
    __syncthreads();

    // out[bn,o] = sum_a att2[a] * att1[a,o]
    if (tid < 32) {
        const int o = tid;
        float s = 0.f;
#pragma unroll
        for (int a = 0; a < 32; ++a)
            s += att2_s[a] * att1_s[a * 33 + o];
        out[bn * 32 + o] = s;
    }
}

extern "C" void kernel_launch(void* const* d_in, const int* in_sizes, int n_in,
                              void* d_out, int out_size, void* d_ws, size_t ws_size,
                              hipStream_t stream) {
    const float* q        = (const float*)d_in[0];
    const float* att1     = (const float*)d_in[1];
    const float* obj_reps = (const float*)d_in[2];
    const int*   tags     = (const int*)d_in[3];
    const float* t_rep    = (const float*)d_in[4];
    const float* W        = (const float*)d_in[5];
    const float* bias_p   = (const float*)d_in[6];
    const int*   t_p      = (const int*)d_in[7];
    float* out = (float*)d_out;

    float* inter = (float*)d_ws;   // 2048*512*4 = 4 MB

    dim3 g1(GN / BN, GM / BM);     // (8, 32) = 256 blocks
    gemm_qw<<<g1, 256, 0, stream>>>(q, W, inter);

    fused_att<<<2048, 256, 0, stream>>>(att1, obj_reps, tags, t_rep, inter,
                                        bias_p, t_p, out);
}

// Round 6
// 234.097 us; speedup vs baseline: 1.0444x; 1.0444x over previous
//
#include <hip/hip_runtime.h>

// Shapes (fixed): B=32, N=64, A=32, O=32, D=512, QD=512
// Inputs: 0:q(B,N,1,QD) f32  1:att1(B,N,A,O) f32  2:obj_reps(B,O,D) f32
//         3:tags(B,N,A) i32  4:t_rep(B,N,A,D) f32 5:W(QD,D) f32
//         6:bias f32 scalar  7:t i32 scalar
// Out: (B,N,O) f32
//
// Restructure: logits[bn,a] = sum_o att1[bn,a,o]*proj[bn,o] + inter[bn,:].t_rep[bn,a,:]
//   proj[bn,o] = inter[bn,:].obj_reps[b,o,:];  inter = q @ W
// Avoids materializing v (134 MB write+read). HBM floor ~= t_rep stream = 134 MB -> ~21 us.
// fp32 everywhere: logits std ~77 with near-one-hot softmax; bf16 noise can flip ties.
//
// FINAL CONFIG = R2 (best measured, 233.5 us). Measurement model from R1-R5:
// dur_us ~= 190-195 us fixed harness traffic (512 MiB ws re-poison ~78 us + input
// restores, all at ~85% HBM peak) + ~40 us our two kernels. Run-to-run noise is
// +/-5-7 us (fill dispatches alone vary 77.0-79.7 us), which covers the entire
// R2..R5 spread (233.5-244.5). Controllable floor ~30 us; residual ~10 us slack
// is below the noise floor and unresolvable by this bench.

#define GM 2048   // B*N
#define GK 512    // QD
#define GN 512    // D

// ---------------- K1: inter = q @ W  (fp32 tiled GEMM, 64x64 tile, 4x4 microtile) ----
// Per kk-step per thread: 2x ds_read_b128 + 16 v_fma_f32 -> VALU-bound (~157 TF ceiling).
#define BM 64
#define BN 64
#define BK 32
#define ASTRIDE (BM + 4)   // 68: rows stay 16B-aligned for ds_read_b128

__global__ __launch_bounds__(256) void gemm_qw(const float* __restrict__ A,
                                               const float* __restrict__ Bm,
                                               float* __restrict__ C) {
    __shared__ float As[BK][ASTRIDE];   // transposed: As[k][m]
    __shared__ float Bs[BK][BN];        // Bs[k][n]

    const int tid = threadIdx.x;
    const int bm0 = blockIdx.y * BM;
    const int bn0 = blockIdx.x * BN;

    // staging: A tile 64x32 = 512 float4 (2/thread), B tile 32x64 = 512 float4 (2/thread)
    const int ar = tid >> 3;            // 0..31 (A row), second row ar+32
    const int ak = (tid & 7) << 2;      // 0..28 (A k, x4)
    const int br = tid >> 4;            // 0..15 (B k), second k br+16
    const int bc = (tid & 15) << 2;     // 0..60 (B col, x4)

    const int tx = tid & 15;            // output col group (cols tx*4..+3)
    const int ty = tid >> 4;            // output row group (rows ty*4..+3)

    float acc[4][4] = {};

    const float* Ab = A + (long)bm0 * GK;
    const float* Bb = Bm + bn0;

    // prefetch tile 0
    float4 a0 = *(const float4*)(Ab + ar * GK + ak);
    float4 a1 = *(const float4*)(Ab + (ar + 32) * GK + ak);
    float4 b0 = *(const float4*)(Bb + br * GN + bc);
    float4 b1 = *(const float4*)(Bb + (br + 16) * GN + bc);

    for (int k0 = 0; k0 < GK; k0 += BK) {
        __syncthreads();   // previous iteration's LDS reads done
        As[ak + 0][ar] = a0.x; As[ak + 1][ar] = a0.y;
        As[ak + 2][ar] = a0.z; As[ak + 3][ar] = a0.w;
        As[ak + 0][ar + 32] = a1.x; As[ak + 1][ar + 32] = a1.y;
        As[ak + 2][ar + 32] = a1.z; As[ak + 3][ar + 32] = a1.w;
        *(float4*)&Bs[br][bc]      = b0;
        *(float4*)&Bs[br + 16][bc] = b1;
        __syncthreads();

        if (k0 + BK < GK) {   // register prefetch of next K-tile hides global latency
            a0 = *(const float4*)(Ab + ar * GK + (k0 + BK) + ak);
            a1 = *(const float4*)(Ab + (ar + 32) * GK + (k0 + BK) + ak);
            b0 = *(const float4*)(Bb + (k0 + BK + br) * GN + bc);
            b1 = *(const float4*)(Bb + (k0 + BK + br + 16) * GN + bc);
        }

#pragma unroll
        for (int kk = 0; kk < BK; ++kk) {
            float4 av = *(const float4*)&As[kk][ty * 4];   // broadcast across 16 lanes
            float4 bv = *(const float4*)&Bs[kk][tx * 4];   // 2-way bank alias (free)
            acc[0][0] += av.x * bv.x; acc[0][1] += av.x * bv.y;
            acc[0][2] += av.x * bv.z; acc[0][3] += av.x * bv.w;
            acc[1][0] += av.y * bv.x; acc[1][1] += av.y * bv.y;
            acc[1][2] += av.y * bv.z; acc[1][3] += av.y * bv.w;
            acc[2][0] += av.z * bv.x; acc[2][1] += av.z * bv.y;
            acc[2][2] += av.z * bv.z; acc[2][3] += av.z * bv.w;
            acc[3][0] += av.w * bv.x; acc[3][1] += av.w * bv.y;
            acc[3][2] += av.w * bv.z; acc[3][3] += av.w * bv.w;
        }
    }

#pragma unroll
    for (int i = 0; i < 4; ++i) {
        float4 v = make_float4(acc[i][0], acc[i][1], acc[i][2], acc[i][3]);
        *(float4*)(C + (long)(bm0 + ty * 4 + i) * GN + bn0 + tx * 4) = v;
    }
}

// ---------------- K2: fused proj/tdot/logits/softmax/output ----------------
// Separate loops: obj_reps pass (L2-resident) then t_rep pass (HBM stream). Keeps
// register pressure low so all 16 t_rep float4 loads stay in flight. No nontemporal
// (R4's merged+nt variant measured worse within noise; this form is best measured).
__global__ __launch_bounds__(256) void fused_att(
    const float* __restrict__ att1, const float* __restrict__ obj_reps,
    const int* __restrict__ tags, const float* __restrict__ t_rep,
    const float* __restrict__ inter, const float* __restrict__ bias_p,
    const int* __restrict__ t_p, float* __restrict__ out) {
    const int bn = blockIdx.x;     // 0..2047
    const int b  = bn >> 6;        // N = 64
    const int tid = threadIdx.x;

    __shared__ float inter_s[512];
    __shared__ float att1_s[32 * 33];   // +1 pad: bank-conflict-free rows & cols
    __shared__ float proj_s[32];
    __shared__ float tdot_s[32];
    __shared__ float att2_s[32];

    // stage inter row (512 f32) and att1 tile (32x32 f32, padded)
    {
        float2 v = *(const float2*)(inter + bn * 512 + tid * 2);
        inter_s[tid * 2 + 0] = v.x;
        inter_s[tid * 2 + 1] = v.y;
    }
    {
        float4 v = *(const float4*)(att1 + bn * 1024 + tid * 4);
        int f = tid * 4;
        int r = f >> 5, c = f & 31;
        att1_s[r * 33 + c + 0] = v.x;
        att1_s[r * 33 + c + 1] = v.y;
        att1_s[r * 33 + c + 2] = v.z;
        att1_s[r * 33 + c + 3] = v.w;
    }
    __syncthreads();

    const int g = tid >> 3;   // 0..31: one row per 8-thread group
    const int j = tid & 7;    // lane within group

    // proj[g] = inter . obj_reps[b,g,:]   (L2-resident: obj_reps is 2 MB)
    {
        const float* p = obj_reps + (b * 32 + g) * 512;
        float s = 0.f;
#pragma unroll
        for (int i = 0; i < 16; ++i) {
            int d = i * 32 + j * 4;
            float4 v = *(const float4*)(p + d);
            s += v.x * inter_s[d + 0] + v.y * inter_s[d + 1]
               + v.z * inter_s[d + 2] + v.w * inter_s[d + 3];
        }
        s += __shfl_xor(s, 1); s += __shfl_xor(s, 2); s += __shfl_xor(s, 4);
        if (j == 0) proj_s[g] = s;
    }
    // tdot[g] = inter . t_rep[bn,g,:]   (the HBM-dominant stream: 134 MB total)
    {
        const float* p = t_rep + (bn * 32 + g) * 512;
        float s = 0.f;
#pragma unroll
        for (int i = 0; i < 16; ++i) {
            int d = i * 32 + j * 4;
            float4 v = *(const float4*)(p + d);
            s += v.x * inter_s[d + 0] + v.y * inter_s[d + 1]
               + v.z * inter_s[d + 2] + v.w * inter_s[d + 3];
        }
        s += __shfl_xor(s, 1); s += __shfl_xor(s, 2); s += __shfl_xor(s, 4);
        if (j == 0) tdot_s[g] = s;
    }
    __syncthreads();

    // logits + masked softmax + renorm: threads 0..31 (all in wave 0)
    if (tid < 32) {
        const int a = tid;
        const float bias = *bias_p;
        const float tt = (float)(*t_p);
        float lsum = tdot_s[a] + bias;
#pragma unroll
        for (int o = 0; o < 32; ++o)
            lsum += att1_s[a * 33 + o] * proj_s[o];
        const float m = (float)tags[bn * 32 + a];
        float x = (lsum / tt) * m;     // masked slots -> logit 0, still in softmax
        float mx = x;
        mx = fmaxf(mx, __shfl_xor(mx, 1));
        mx = fmaxf(mx, __shfl_xor(mx, 2));
        mx = fmaxf(mx, __shfl_xor(mx, 4));
        mx = fmaxf(mx, __shfl_xor(mx, 8));
        mx = fmaxf(mx, __shfl_xor(mx, 16));
        float e = __expf(x - mx);
        float den = e;
        den += __shfl_xor(den, 1);
        den += __shfl_xor(den, 2);
        den += __shfl_xor(den, 4);
        den += __shfl_xor(den, 8);
        den += __shfl_xor(den, 16);
        float s = (e / den) * m;
        float ss = s;
        ss += __shfl_xor(ss, 1);
        ss += __shfl_xor(ss, 2);
        ss += __shfl_xor(ss, 4);
        ss += __shfl_xor(ss, 8);
        ss += __shfl_xor(ss, 16);
        att2_s[a] = s / (ss + 1e-13f);
    }
    __syncthreads();

    // out[bn,o] = sum_a att2[a] * att1[a,o]
    if (tid < 32) {
        const int o = tid;
        float s = 0.f;
#pragma unroll
        for (int a = 0; a < 32; ++a)
            s += att2_s[a] * att1_s[a * 33 + o];
        out[bn * 32 + o] = s;
    }
}

extern "C" void kernel_launch(void* const* d_in, const int* in_sizes, int n_in,
                              void* d_out, int out_size, void* d_ws, size_t ws_size,
                              hipStream_t stream) {
    const float* q        = (const float*)d_in[0];
    const float* att1     = (const float*)d_in[1];
    const float* obj_reps = (const float*)d_in[2];
    const int*   tags     = (const int*)d_in[3];
    const float* t_rep    = (const float*)d_in[4];
    const float* W        = (const float*)d_in[5];
    const float* bias_p   = (const float*)d_in[6];
    const int*   t_p      = (const int*)d_in[7];
    float* out = (float*)d_out;

    float* inter = (float*)d_ws;   // 2048*512*4 = 4 MB

    dim3 g1(GN / BN, GM / BM);     // (8, 32) = 256 blocks
    gemm_qw<<<g1, 256, 0, stream>>>(q, W, inter);

    fused_att<<<2048, 256, 0, stream>>>(att1, obj_reps, tags, t_rep, inter,
                                        bias_p, t_p, out);
}

// Round 7
// 230.583 us; speedup vs baseline: 1.0604x; 1.0152x over previous
//
#include <hip/hip_runtime.h>

// Shapes (fixed): B=32, N=64, A=32, O=32, D=512, QD=512
// Inputs: 0:q(B,N,1,QD) f32  1:att1(B,N,A,O) f32  2:obj_reps(B,O,D) f32
//         3:tags(B,N,A) i32  4:t_rep(B,N,A,D) f32 5:W(QD,D) f32
//         6:bias f32 scalar  7:t i32 scalar
// Out: (B,N,O) f32
//
// Restructure: logits[bn,a] = sum_o att1[bn,a,o]*proj[bn,o] + inter[bn,:].t_rep[bn,a,:]
//   proj[bn,o] = inter[bn,:].obj_reps[b,o,:];  inter = q @ W
// Avoids materializing v (134 MB write+read). HBM floor ~= t_rep stream = 134 MB -> ~21 us.
// fp32 everywhere: logits std ~77 with near-one-hot softmax; bf16 noise can flip ties.
//
// Measurement model (R1-R6): same-binary repeatability +/-0.5 us (R2=233.5, R6=234.1).
// Factorized deltas: K1-BK64-regtranspose = +11.0 us (UNCOALESCED A staging: adjacent
// lanes 8 KB apart); K2-merged+nt = -4.6 us (2x memory-level parallelism + nt keeps
// L2 for obj_reps/att1). This config = R2's K1 (coalesced, BK=32) + R4's K2 (merged+nt).

// native vector type: __builtin_nontemporal_load rejects HIP_vector_type pointers
typedef float floatx4 __attribute__((ext_vector_type(4)));

#define GM 2048   // B*N
#define GK 512    // QD
#define GN 512    // D

// ---------------- K1: inter = q @ W  (fp32 tiled GEMM, 64x64 tile, 4x4 microtile) ----
// Per kk-step per thread: 2x ds_read_b128 + 16 v_fma_f32 -> VALU-bound (~157 TF ceiling).
// Staging keeps adjacent lanes on adjacent addresses (coalesced) — do NOT trade this
// for wider LDS writes (R4/R5 lesson: -11 us).
#define BM 64
#define BN 64
#define BK 32
#define ASTRIDE (BM + 4)   // 68: rows stay 16B-aligned for ds_read_b128

__global__ __launch_bounds__(256) void gemm_qw(const float* __restrict__ A,
                                               const float* __restrict__ Bm,
                                               float* __restrict__ C) {
    __shared__ float As[BK][ASTRIDE];   // transposed: As[k][m]
    __shared__ float Bs[BK][BN];        // Bs[k][n]

    const int tid = threadIdx.x;
    const int bm0 = blockIdx.y * BM;
    const int bn0 = blockIdx.x * BN;

    // staging: A tile 64x32 = 512 float4 (2/thread), B tile 32x64 = 512 float4 (2/thread)
    const int ar = tid >> 3;            // 0..31 (A row), second row ar+32
    const int ak = (tid & 7) << 2;      // 0..28 (A k, x4)
    const int br = tid >> 4;            // 0..15 (B k), second k br+16
    const int bc = (tid & 15) << 2;     // 0..60 (B col, x4)

    const int tx = tid & 15;            // output col group (cols tx*4..+3)
    const int ty = tid >> 4;            // output row group (rows ty*4..+3)

    float acc[4][4] = {};

    const float* Ab = A + (long)bm0 * GK;
    const float* Bb = Bm + bn0;

    // prefetch tile 0
    float4 a0 = *(const float4*)(Ab + ar * GK + ak);
    float4 a1 = *(const float4*)(Ab + (ar + 32) * GK + ak);
    float4 b0 = *(const float4*)(Bb + br * GN + bc);
    float4 b1 = *(const float4*)(Bb + (br + 16) * GN + bc);

    for (int k0 = 0; k0 < GK; k0 += BK) {
        __syncthreads();   // previous iteration's LDS reads done
        As[ak + 0][ar] = a0.x; As[ak + 1][ar] = a0.y;
        As[ak + 2][ar] = a0.z; As[ak + 3][ar] = a0.w;
        As[ak + 0][ar + 32] = a1.x; As[ak + 1][ar + 32] = a1.y;
        As[ak + 2][ar + 32] = a1.z; As[ak + 3][ar + 32] = a1.w;
        *(float4*)&Bs[br][bc]      = b0;
        *(float4*)&Bs[br + 16][bc] = b1;
        __syncthreads();

        if (k0 + BK < GK) {   // register prefetch of next K-tile hides global latency
            a0 = *(const float4*)(Ab + ar * GK + (k0 + BK) + ak);
            a1 = *(const float4*)(Ab + (ar + 32) * GK + (k0 + BK) + ak);
            b0 = *(const float4*)(Bb + (k0 + BK + br) * GN + bc);
            b1 = *(const float4*)(Bb + (k0 + BK + br + 16) * GN + bc);
        }

#pragma unroll
        for (int kk = 0; kk < BK; ++kk) {
            float4 av = *(const float4*)&As[kk][ty * 4];   // broadcast across 16 lanes
            float4 bv = *(const float4*)&Bs[kk][tx * 4];   // 2-way bank alias (free)
            acc[0][0] += av.x * bv.x; acc[0][1] += av.x * bv.y;
            acc[0][2] += av.x * bv.z; acc[0][3] += av.x * bv.w;
            acc[1][0] += av.y * bv.x; acc[1][1] += av.y * bv.y;
            acc[1][2] += av.y * bv.z; acc[1][3] += av.y * bv.w;
            acc[2][0] += av.z * bv.x; acc[2][1] += av.z * bv.y;
            acc[2][2] += av.z * bv.z; acc[2][3] += av.z * bv.w;
            acc[3][0] += av.w * bv.x; acc[3][1] += av.w * bv.y;
            acc[3][2] += av.w * bv.z; acc[3][3] += av.w * bv.w;
        }
    }

#pragma unroll
    for (int i = 0; i < 4; ++i) {
        float4 v = make_float4(acc[i][0], acc[i][1], acc[i][2], acc[i][3]);
        *(float4*)(C + (long)(bm0 + ty * 4 + i) * GN + bn0 + tx * 4) = v;
    }
}

// ---------------- K2: fused proj/tdot/logits/softmax/output (merged + nt) ----------
// proj (L2) + tdot (HBM) in ONE loop: 2x memory-level parallelism per wave; inter_s
// read once for both dots. t_rep nontemporal: the 134 MB single-use stream must not
// evict obj_reps/att1 from L2. Measured -4.6 us vs separate loops (R4 vs R5).
__global__ __launch_bounds__(256) void fused_att(
    const float* __restrict__ att1, const float* __restrict__ obj_reps,
    const int* __restrict__ tags, const float* __restrict__ t_rep,
    const float* __restrict__ inter, const float* __restrict__ bias_p,
    const int* __restrict__ t_p, float* __restrict__ out) {
    const int bn = blockIdx.x;     // 0..2047
    const int b  = bn >> 6;        // N = 64
    const int tid = threadIdx.x;

    __shared__ float inter_s[512];
    __shared__ float att1_s[32 * 33];   // +1 pad: bank-conflict-free rows & cols
    __shared__ float proj_s[32];
    __shared__ float tdot_s[32];
    __shared__ float att2_s[32];

    // stage inter row (512 f32) and att1 tile (32x32 f32, padded)
    {
        float2 v = *(const float2*)(inter + bn * 512 + tid * 2);
        inter_s[tid * 2 + 0] = v.x;
        inter_s[tid * 2 + 1] = v.y;
    }
    {
        float4 v = *(const float4*)(att1 + bn * 1024 + tid * 4);
        int f = tid * 4;
        int r = f >> 5, c = f & 31;
        att1_s[r * 33 + c + 0] = v.x;
        att1_s[r * 33 + c + 1] = v.y;
        att1_s[r * 33 + c + 2] = v.z;
        att1_s[r * 33 + c + 3] = v.w;
    }
    __syncthreads();

    const int g = tid >> 3;   // 0..31: one row per 8-thread group
    const int j = tid & 7;    // lane within group

    {
        const float* pt = t_rep    + (bn * 32 + g) * 512;   // HBM stream (134 MB total)
        const float* po = obj_reps + (b  * 32 + g) * 512;   // L2-resident (2 MB)
        float st = 0.f, sp = 0.f;
#pragma unroll
        for (int i = 0; i < 16; ++i) {
            int d = i * 32 + j * 4;
            floatx4 tv = __builtin_nontemporal_load((const floatx4*)(pt + d));
            float4 ov = *(const float4*)(po + d);
            float i0 = inter_s[d + 0], i1 = inter_s[d + 1];
            float i2 = inter_s[d + 2], i3 = inter_s[d + 3];
            st += tv.x * i0 + tv.y * i1 + tv.z * i2 + tv.w * i3;
            sp += ov.x * i0 + ov.y * i1 + ov.z * i2 + ov.w * i3;
        }
        st += __shfl_xor(st, 1); st += __shfl_xor(st, 2); st += __shfl_xor(st, 4);
        sp += __shfl_xor(sp, 1); sp += __shfl_xor(sp, 2); sp += __shfl_xor(sp, 4);
        if (j == 0) { tdot_s[g] = st; proj_s[g] = sp; }
    }
    __syncthreads();

    // logits + masked softmax + renorm: threads 0..31 (all in wave 0)
    if (tid < 32) {
        const int a = tid;
        const float bias = *bias_p;
        const float tt = (float)(*t_p);
        float lsum = tdot_s[a] + bias;
#pragma unroll
        for (int o = 0; o < 32; ++o)
            lsum += att1_s[a * 33 + o] * proj_s[o];
        const float m = (float)tags[bn * 32 + a];
        float x = (lsum / tt) * m;     // masked slots -> logit 0, still in softmax
        float mx = x;
        mx = fmaxf(mx, __shfl_xor(mx, 1));
        mx = fmaxf(mx, __shfl_xor(mx, 2));
        mx = fmaxf(mx, __shfl_xor(mx, 4));
        mx = fmaxf(mx, __shfl_xor(mx, 8));
        mx = fmaxf(mx, __shfl_xor(mx, 16));
        float e = __expf(x - mx);
        float den = e;
        den += __shfl_xor(den, 1);
        den += __shfl_xor(den, 2);
        den += __shfl_xor(den, 4);
        den += __shfl_xor(den, 8);
        den += __shfl_xor(den, 16);
        float s = (e / den) * m;
        float ss = s;
        ss += __shfl_xor(ss, 1);
        ss += __shfl_xor(ss, 2);
        ss += __shfl_xor(ss, 4);
        ss += __shfl_xor(ss, 8);
        ss += __shfl_xor(ss, 16);
        att2_s[a] = s / (ss + 1e-13f);
    }
    __syncthreads();

    // out[bn,o] = sum_a att2[a] * att1[a,o]
    if (tid < 32) {
        const int o = tid;
        float s = 0.f;
#pragma unroll
        for (int a = 0; a < 32; ++a)
            s += att2_s[a] * att1_s[a * 33 + o];
        out[bn * 32 + o] = s;
    }
}

extern "C" void kernel_launch(void* const* d_in, const int* in_sizes, int n_in,
                              void* d_out, int out_size, void* d_ws, size_t ws_size,
                              hipStream_t stream) {
    const float* q        = (const float*)d_in[0];
    const float* att1     = (const float*)d_in[1];
    const float* obj_reps = (const float*)d_in[2];
    const int*   tags     = (const int*)d_in[3];
    const float* t_rep    = (const float*)d_in[4];
    const float* W        = (const float*)d_in[5];
    const float* bias_p   = (const float*)d_in[6];
    const int*   t_p      = (const int*)d_in[7];
    float* out = (float*)d_out;

    float* inter = (float*)d_ws;   // 2048*512*4 = 4 MB

    dim3 g1(GN / BN, GM / BM);     // (8, 32) = 256 blocks
    gemm_qw<<<g1, 256, 0, stream>>>(q, W, inter);

    fused_att<<<2048, 256, 0, stream>>>(att1, obj_reps, tags, t_rep, inter,
                                        bias_p, t_p, out);
}